// Round 16
// baseline (258.986 us; speedup 1.0000x reference)
//
#include <hip/hip_runtime.h>
#include <hip/hip_fp16.h>

typedef _Float16 f16;
typedef _Float16 f16x8 __attribute__((ext_vector_type(8)));
typedef float f32x4 __attribute__((ext_vector_type(4)));

#define NB 512
#define NL 16
#define NK 10000
#define NH 128
#define NSF 316    // Wf 32-k sub-steps, zero-padded
#define NT 79      // 128-k tiles

__device__ __forceinline__ float fast_exp2(float x) {
#if __has_builtin(__builtin_amdgcn_exp2f)
  return __builtin_amdgcn_exp2f(x);
#else
  return exp2f(x);
#endif
}
__device__ __forceinline__ float fast_rcp(float x) {
#if __has_builtin(__builtin_amdgcn_rcpf)
  return __builtin_amdgcn_rcpf(x);
#else
  return 1.f / x;
#endif
}
__device__ __forceinline__ float sigf(float x) {
  return fast_rcp(1.f + fast_exp2(-1.44269504f * x));
}
__device__ __forceinline__ float tanh_fast(float x) {
  return 2.f * fast_rcp(1.f + fast_exp2(-2.88539008f * x)) - 1.f;
}

// ---------------------------------------------------------------- prep ------
// Wf: B in MFMA-fragment order: [s][nt][lane][e] with lane=(kg*16+lr),
// value = Wnode[col=nt*16+lr][k=s*32+kg*8+e], zero-padded past K=10000.
__global__ void prep_kernel(
    const float* __restrict__ x, const float* __restrict__ t0,
    const float* __restrict__ tau, const float* __restrict__ endi,
    const float* __restrict__ coords,
    const float* __restrict__ Wx1, const float* __restrict__ Wx2,
    const float* __restrict__ bx2, const float* __restrict__ Wres,
    const float* __restrict__ bres, const float* __restrict__ Wnode,
    const float* __restrict__ Wtau, const float* __restrict__ btau,
    const float* __restrict__ Wend1, const float* __restrict__ Wend2,
    const float* __restrict__ bend2, const float* __restrict__ Wcoord,
    const float* __restrict__ Wih, const float* __restrict__ Whh,
    const float* __restrict__ bih, const float* __restrict__ bhh,
    f16* __restrict__ xh, f16* __restrict__ t0h, f16* __restrict__ endh,
    f16* __restrict__ tauh, f16* __restrict__ coordh, f16* __restrict__ Wf,
    f16* __restrict__ Wih16, f16* __restrict__ Whh16, float* __restrict__ bsum) {
  const int tid0 = blockIdx.x * blockDim.x + threadIdx.x;
  const int stride = gridDim.x * blockDim.x;

  const int nWf = NSF * 4096;
  const int nW = 7 * 512 * NH;      // 458,752
  const int nb = 7 * 512;
  const int nxh = NB * NH;          // 65,536
  const int ntau = NB * NL * NH;    // 1,048,576
  const int nco = NB * 2 * NL * NH; // 2,097,152

  for (int i = tid0; i < nWf; i += stride) {
    const int s = i >> 12, r = i & 4095;
    const int nt = r >> 9, l2 = r & 511;
    const int lane = l2 >> 3, e = l2 & 7;
    const int kg = lane >> 4, lr = lane & 15;
    const int col = nt * 16 + lr;
    const int k = s * 32 + kg * 8 + e;
    Wf[i] = (k < NK) ? (f16)Wnode[(size_t)col * NK + k] : (f16)0.f;
  }
  for (int i = tid0; i < nW; i += stride) {
    Wih16[i] = (f16)Wih[i];
    Whh16[i] = (f16)Whh[i];
  }
  for (int i = tid0; i < nb; i += stride) bsum[i] = bih[i] + bhh[i];
  for (int i = tid0; i < nxh; i += stride) {
    const int b = i >> 7, h = i & 127;
    const float s = x[2 * b] * Wx1[0] + x[2 * b + 1] * Wx1[1];
    xh[i] = (f16)tanhf(s * Wx2[h] + bx2[h]);
    t0h[i] = (f16)tanhf(t0[b] * Wres[h] + bres[h]);
    const float e = endi[2 * b] * Wend1[0] + endi[2 * b + 1] * Wend1[1];
    endh[i] = (f16)(e * Wend2[h] + bend2[h]);
  }
  for (int i = tid0; i < ntau; i += stride) {
    const int h = i & 127, bl = i >> 7;
    tauh[i] = (f16)tanhf(tau[bl] * Wtau[h] + btau[h]);
  }
  for (int i = tid0; i < nco; i += stride) {
    const int h = i & 127, br = i >> 7;
    coordh[i] = (f16)(coords[2 * br] * Wcoord[2 * h] +
                      coords[2 * br + 1] * Wcoord[2 * h + 1]);
  }
}

// ------------------------------------------------------------ node GEMM -----
// C(16384x128,f16) = A(16384x10000,f32) * W^T. Grid 256 wgs x 64 rows,
// full K. Tile = 64 rows x 128 k f32 (32 KB); ring-4 = 128 KB LDS. A staged
// via plain dwordx4 -> VGPR -> swizzled ds_write_b128 (R15).
// KEY CHANGE vs R15: COUNTED s_waitcnt vmcnt(4) retires exactly {A(t) issued
// 2 iters ago, B(t) issued 1 iter ago}; A(t+1) stays in flight ACROSS the
// barrier -> every A-load gets ~2 iterations (>4000 cyc) of latency cover
// and the CU's HBM queue never drains (R15's per-iter vmcnt(0) exposed the
// full load latency every tile). Prologue issues in steady-state FIFO order
// (A0, B0, A1). Wave = (kw: 64-k half, cp: 32 cols); B 1x redundancy;
// kw-combine via LDS bounce in the epilogue.
__global__ __launch_bounds__(512, 2) void node_gemm(const float* __restrict__ A,
                                                    const f16* __restrict__ Wf,
                                                    f16* __restrict__ Cn) {
  __shared__ char lds[4][32768];
  const int tid = threadIdx.x;
  const int w = tid >> 6, l = tid & 63;
  const int lr = l & 15, kg = l >> 4;
  const int r0 = blockIdx.x * 64;
  char* lds0 = &lds[0][0];

  // ---- staging: instr i covers rows w*8+i*2+(l>>5); lanes 0-31 = one row's
  // 512-B tile chunk (plain linear source). ds_write dest is swizzled.
  const char* ap[4];
  int bnd[4], wdo[4];
#pragma unroll
  for (int i = 0; i < 4; i++) {
    const int row = w * 8 + i * 2 + (l >> 5);
    const int off = (l & 31) * 16;
    ap[i] = (const char*)A + (size_t)(r0 + row) * 40000 + off;
    bnd[i] = 39984 - off;  // clamp keeps 16B in-bounds; Wf zero-pad kills it
    wdo[i] = row * 512 + (off ^ ((row & 7) << 4));
  }

  // ---- compute: wave = (kw = w&1: 64-k half, cp = w>>1: 32 cols) ----
  const int kw = w & 1, cp = w >> 1;
  int rdoA[4][2][2];  // [row-group][k-slice][half]
#pragma unroll
  for (int rg = 0; rg < 4; rg++) {
    const int row = rg * 16 + lr;
    const int sw = (row & 7) << 4;
#pragma unroll
    for (int ks = 0; ks < 2; ks++)
#pragma unroll
      for (int h = 0; h < 2; h++)
        rdoA[rg][ks][h] =
            row * 512 + ((kw * 256 + ks * 128 + kg * 32 + h * 16) ^ sw);
  }

  f32x4 acc[4][2];
#pragma unroll
  for (int rg = 0; rg < 4; rg++)
#pragma unroll
    for (int j = 0; j < 2; j++) {
      f32x4 z = {0.f, 0.f, 0.f, 0.f};
      acc[rg][j] = z;
    }

  auto loadA = [&](int t, f32x4 (&r)[4]) {
    const int tb = t * 512;
#pragma unroll
    for (int i = 0; i < 4; i++) {
      const int off = tb < bnd[i] ? tb : bnd[i];
      r[i] = *(const f32x4*)(ap[i] + off);
    }
  };

  auto dswrite = [&](int t, const f32x4 (&r)[4]) {
    char* db = lds0 + (t & 3) * 32768;
#pragma unroll
    for (int i = 0; i < 4; i++) *(f32x4*)(db + wdo[i]) = r[i];
  };

  // this wave's unique B share for 128-k tile t: 2 cols x 2 k-slices
  auto loadB = [&](int t, f16x8 (&B)[2][2]) {
    const f16* bp = Wf + (size_t)(4 * t + 2 * kw) * 4096 + cp * 1024 + l * 8;
#pragma unroll
    for (int j = 0; j < 2; j++)
#pragma unroll
      for (int ks = 0; ks < 2; ks++)
        B[j][ks] = *(const f16x8*)(bp + (size_t)ks * 4096 + j * 512);
  };

  auto compute = [&](int t, const f16x8 (&B)[2][2]) {
    const char* cb = lds0 + (t & 3) * 32768;
#pragma unroll
    for (int ks = 0; ks < 2; ks++)
#pragma unroll
      for (int rg = 0; rg < 4; rg++) {
        const f32x4 a0 = *(const f32x4*)(cb + rdoA[rg][ks][0]);
        const f32x4 a1 = *(const f32x4*)(cb + rdoA[rg][ks][1]);
        f16x8 af;
        af[0] = (f16)a0[0]; af[1] = (f16)a0[1];
        af[2] = (f16)a0[2]; af[3] = (f16)a0[3];
        af[4] = (f16)a1[0]; af[5] = (f16)a1[1];
        af[6] = (f16)a1[2]; af[7] = (f16)a1[3];
#pragma unroll
        for (int j = 0; j < 2; j++)
          acc[rg][j] = __builtin_amdgcn_mfma_f32_16x16x32_f16(
              af, B[j][ks], acc[rg][j], 0, 0, 0);
      }
  };

  f32x4 RA0[4], RA1[4];
  f16x8 B0[2][2], B1[2][2];

  // prologue in steady-state FIFO order: A(0), B(0), A(1)
  loadA(0, RA0);
  loadB(0, B0);
  loadA(1, RA1);

  for (int e = 0; e + 1 < NT; e += 2) {
    // ---- iter e: retire A(e)[RA0, issued 2 iters ago] + B(e)[B0];
    //      A(e+1)[RA1, 4 loads] stays in flight across the barrier.
    asm volatile("s_waitcnt vmcnt(4)" ::: "memory");
    dswrite(e, RA0);
    loadB(e + 1, B1);
    loadA(e + 2, RA0);
    asm volatile("s_waitcnt lgkmcnt(0)" ::: "memory");
    __builtin_amdgcn_s_barrier();
    compute(e, B0);
    // ---- iter e+1: retire A(e+1)[RA1] + B(e+1)[B1]; A(e+2) stays.
    asm volatile("s_waitcnt vmcnt(4)" ::: "memory");
    dswrite(e + 1, RA1);
    loadB(e + 2, B0);
    if (e + 3 < NT) loadA(e + 3, RA1);
    asm volatile("s_waitcnt lgkmcnt(0)" ::: "memory");
    __builtin_amdgcn_s_barrier();
    compute(e + 1, B1);
  }
  // tail tile 78 (NT odd): outstanding = A(78)[RA0] + B(78)[B0]
  asm volatile("s_waitcnt vmcnt(0)" ::: "memory");
  dswrite(NT - 1, RA0);
  asm volatile("s_waitcnt lgkmcnt(0)" ::: "memory");
  __builtin_amdgcn_s_barrier();
  compute(NT - 1, B0);

  // ---- combine kw halves via LDS bounce, then write C f16 ----
  __syncthreads();  // all computes done
  if (kw == 1) {
#pragma unroll
    for (int rg = 0; rg < 4; rg++)
#pragma unroll
      for (int j = 0; j < 2; j++) {
        const int tl = cp * 8 + rg * 2 + j;
        *(f32x4*)(lds0 + tl * 1024 + l * 16) = acc[rg][j];
      }
  }
  __syncthreads();
  if (kw == 0) {
#pragma unroll
    for (int rg = 0; rg < 4; rg++)
#pragma unroll
      for (int j = 0; j < 2; j++) {
        const int tl = cp * 8 + rg * 2 + j;
        const f32x4 p = *(const f32x4*)(lds0 + tl * 1024 + l * 16);
        const f32x4 s = acc[rg][j] + p;
        f16* crow =
            Cn + (size_t)(r0 + rg * 16 + kg * 4) * NH + cp * 32 + j * 16 + lr;
#pragma unroll
        for (int jr = 0; jr < 4; jr++) crow[(size_t)jr * NH] = (f16)s[jr];
      }
  }
}

// --------------------------------------------------------------- LSTM -------
// grid: 7 k's x 32 batch-chunks of 16. One wg = 8 waves (512 thr); wave w
// owns hidden units [w*16, w*16+16) across all four gates (4 gate-tiles).
// Wih/Whh fragments in VGPRs (~128), x prefetched 1 step ahead. x-MFMAs run
// before h-MFMAs so the ds_read(h) latency hides under them.
__global__ __launch_bounds__(512, 2) void lstm_run(
    const f16* __restrict__ xh, const f16* __restrict__ t0h,
    const f16* __restrict__ endh, const f16* __restrict__ tauh,
    const f16* __restrict__ nodeh, const f16* __restrict__ coordh,
    const f16* __restrict__ Wih16, const f16* __restrict__ Whh16,
    const float* __restrict__ bsum, const float* __restrict__ hW1,
    const float* __restrict__ hb1, const float* __restrict__ hW2,
    const float* __restrict__ hb2, float* __restrict__ out) {
  __shared__ f16 hbuf[2][16 * NH];  // double-buffered h, XOR-swizzled bytes
  __shared__ float hu[16 * NH];

  const int k = blockIdx.x >> 5;
  const int b0 = (blockIdx.x & 31) << 4;
  const int w = threadIdx.x >> 6;
  const int l = threadIdx.x & 63;
  const int lr = l & 15, kg = l >> 4;

  int len;
  switch (k) {
    case 0: len = 83; break;
    case 1: len = 19; break;
    case 2: len = 32; break;
    case 3: len = 32; break;
    case 4: len = 51; break;
    case 5: len = 64; break;
    default: len = 51; break;
  }

  // per-step input fragment pointer (wave-uniform select logic)
  auto xptr = [&](int t) -> const f16* {
    const f16* cb; int bstr, idx;
    if (k == 2) { cb = nodeh; bstr = 32 * NH; idx = t; }
    else if (k == 3) { cb = coordh; bstr = 32 * NH; idx = t; }
    else if (k == 5) {
      const int q = t >> 2, r = t & 3;
      cb = (r == 0 || r == 2) ? nodeh : coordh;
      bstr = 32 * NH;
      idx = 2 * q + ((r >= 2) ? 1 : 0);
    } else {
      if (t == 0) { cb = xh; bstr = NH; idx = 0; }
      else if (t == 1) { cb = t0h; bstr = NH; idx = 0; }
      else if (t == len - 1) { cb = endh; bstr = NH; idx = 0; }
      else {
        const int u = t - 2;
        if (k == 0) {
          const int q = u / 5, r = u - 5 * q;
          if (r == 0) { cb = tauh; bstr = 16 * NH; idx = q; }
          else if (r == 1) { cb = nodeh; bstr = 32 * NH; idx = 2 * q; }
          else if (r == 2) { cb = coordh; bstr = 32 * NH; idx = 2 * q; }
          else if (r == 3) { cb = nodeh; bstr = 32 * NH; idx = 2 * q + 1; }
          else { cb = coordh; bstr = 32 * NH; idx = 2 * q + 1; }
        } else if (k == 1) { cb = tauh; bstr = 16 * NH; idx = u; }
        else if (k == 4) {
          const int q = u / 3, r = u - 3 * q;
          if (r == 0) { cb = tauh; bstr = 16 * NH; idx = q; }
          else { cb = nodeh; bstr = 32 * NH; idx = 2 * q + (r - 1); }
        } else {  // k == 6
          const int q = u / 3, r = u - 3 * q;
          if (r == 0) { cb = tauh; bstr = 16 * NH; idx = q; }
          else { cb = coordh; bstr = 32 * NH; idx = 2 * q + (r - 1); }
        }
      }
    }
    return cb + (size_t)(b0 + lr) * bstr + idx * NH + kg * 8;
  };

  // ---- load weight fragments into registers ----
  // wave w owns hidden cols [w*16, w*16+16); gate g's row block = g*128.
  f16x8 Wh[4][4], Wi[4][4];
  float bias[4];
  {
    const f16* whb = Whh16 + (size_t)k * 512 * NH;
    const f16* wib = Wih16 + (size_t)k * 512 * NH;
#pragma unroll
    for (int g = 0; g < 4; g++) {
      const int col = g * 128 + w * 16 + lr;
      bias[g] = bsum[k * 512 + col];
#pragma unroll
      for (int kc = 0; kc < 4; kc++) {
        Wh[kc][g] = *(const f16x8*)(whb + (size_t)col * NH + kc * 32 + kg * 8);
        Wi[kc][g] = *(const f16x8*)(wib + (size_t)col * NH + kc * 32 + kg * 8);
      }
    }
  }

  char* lds0 = (char*)&hbuf[0][0];
  // zero h buffer 0 (h0 = 0): 512 threads x 8 B = 4096 B
  *(unsigned long long*)(lds0 + threadIdx.x * 8) = 0ull;
  __syncthreads();

  float c[4] = {0, 0, 0, 0};

  // precomputed swizzled LDS byte offsets (constant across t)
  int rdo[4];
#pragma unroll
  for (int kc = 0; kc < 4; kc++) {
    const int colb = (kc * 32 + kg * 8) * 2;
    rdo[kc] = lr * 256 + (colb ^ ((lr & 7) << 4));
  }
  int wro[4];
#pragma unroll
  for (int jr = 0; jr < 4; jr++) {
    const int hrow = kg * 4 + jr;
    const int hcol = w * 16 + lr;
    wro[jr] = hrow * 256 + ((hcol * 2) ^ ((hrow & 7) << 4));
  }

  // prime x for t=0
  f16x8 axc[4];
  {
    const f16* xp = xptr(0);
#pragma unroll
    for (int kc = 0; kc < 4; kc++) axc[kc] = *(const f16x8*)(xp + kc * 32);
  }

  int cur = 0;
  for (int t = 0; t < len; t++) {
    char* rb = lds0 + cur * 4096;
    f16x8 ah[4];
#pragma unroll
    for (int kc = 0; kc < 4; kc++) ah[kc] = *(const f16x8*)(rb + rdo[kc]);

    // prefetch next-step x into registers (hidden under MFMA+gates+barrier)
    f16x8 axn[4];
    if (t + 1 < len) {
      const f16* xp = xptr(t + 1);
#pragma unroll
      for (int kc = 0; kc < 4; kc++) axn[kc] = *(const f16x8*)(xp + kc * 32);
    }

    f32x4 acc[4];
#pragma unroll
    for (int g = 0; g < 4; g++) {
      f32x4 binit = {bias[g], bias[g], bias[g], bias[g]};
      acc[g] = binit;
    }
    // x-part first (register operands ready) -> hides ds_read(h) latency
#pragma unroll
    for (int kc = 0; kc < 4; kc++)
#pragma unroll
      for (int g = 0; g < 4; g++)
        acc[g] = __builtin_amdgcn_mfma_f32_16x16x32_f16(axc[kc], Wi[kc][g], acc[g], 0, 0, 0);
#pragma unroll
    for (int kc = 0; kc < 4; kc++)
#pragma unroll
      for (int g = 0; g < 4; g++)
        acc[g] = __builtin_amdgcn_mfma_f32_16x16x32_f16(ah[kc], Wh[kc][g], acc[g], 0, 0, 0);

    // gates: acc[0]=i acc[1]=f acc[2]=g acc[3]=o
    char* wb = lds0 + (cur ^ 1) * 4096;
#pragma unroll
    for (int jr = 0; jr < 4; jr++) {
      const float iv = acc[0][jr];
      const float fv = acc[1][jr];
      const float gv = acc[2][jr];
      const float ov = acc[3][jr];
      const float cn = sigf(fv) * c[jr] + sigf(iv) * tanh_fast(gv);
      c[jr] = cn;
      const float hn = sigf(ov) * tanh_fast(cn);
      *(f16*)(wb + wro[jr]) = (f16)hn;
    }
    __syncthreads();
#pragma unroll
    for (int kc = 0; kc < 4; kc++) axc[kc] = axn[kc];
    cur ^= 1;
  }

  // ---- head: out = tanh(h @ W1^T + b1) @ W2^T + b2 ----
  {
    char* rb = lds0 + cur * 4096;
    f16x8 ah[4];
#pragma unroll
    for (int kc = 0; kc < 4; kc++) ah[kc] = *(const f16x8*)(rb + rdo[kc]);
    const float* W1 = hW1 + (size_t)k * NH * NH;
    const int col = w * 16 + lr;
    f32x4 hacc;
    {
      const float b1 = hb1[k * NH + col];
      f32x4 binit = {b1, b1, b1, b1};
      hacc = binit;
    }
#pragma unroll
    for (int kc = 0; kc < 4; kc++) {
      const float* wrow = W1 + (size_t)col * NH + kc * 32 + kg * 8;
      const f32x4 w0 = *(const f32x4*)(wrow);
      const f32x4 w1 = *(const f32x4*)(wrow + 4);
      f16x8 wv;
      wv[0] = (f16)w0[0]; wv[1] = (f16)w0[1]; wv[2] = (f16)w0[2]; wv[3] = (f16)w0[3];
      wv[4] = (f16)w1[0]; wv[5] = (f16)w1[1]; wv[6] = (f16)w1[2]; wv[7] = (f16)w1[3];
      hacc = __builtin_amdgcn_mfma_f32_16x16x32_f16(ah[kc], wv, hacc, 0, 0, 0);
    }
#pragma unroll
    for (int jr = 0; jr < 4; jr++)
      hu[(kg * 4 + jr) * NH + col] = tanh_fast(hacc[jr]);
  }
  __syncthreads();
  if (w == 0) {
    const int b = l >> 2, part = l & 3;
    const float* W2 = hW2 + (size_t)k * NH;
    float s = 0.f;
#pragma unroll
    for (int j = 0; j < 32; j++)
      s += hu[b * NH + part * 32 + j] * W2[part * 32 + j];
    s += __shfl_xor(s, 1);
    s += __shfl_xor(s, 2);
    if (part == 0) out[k * NB + b0 + b] = s + hb2[k];
  }
}

// ------------------------------------------------------------- launch -------
extern "C" void kernel_launch(void* const* d_in, const int* in_sizes, int n_in,
                              void* d_out, int out_size, void* d_ws, size_t ws_size,
                              hipStream_t stream) {
  (void)in_sizes; (void)n_in; (void)out_size; (void)ws_size;
  const float* x = (const float*)d_in[0];
  const float* t0 = (const float*)d_in[1];
  const float* node = (const float*)d_in[2];
  const float* tau = (const float*)d_in[3];
  const float* endi = (const float*)d_in[4];
  const float* coords = (const float*)d_in[5];
  const float* Wx1 = (const float*)d_in[6];
  const float* Wx2 = (const float*)d_in[7];
  const float* bx2 = (const float*)d_in[8];
  const float* Wres = (const float*)d_in[9];
  const float* bres = (const float*)d_in[10];
  const float* Wnode = (const float*)d_in[11];
  const float* Wtau = (const float*)d_in[12];
  const float* btau = (const float*)d_in[13];
  const float* Wend1 = (const float*)d_in[14];
  const float* Wend2 = (const float*)d_in[15];
  const float* bend2 = (const float*)d_in[16];
  const float* Wcoord = (const float*)d_in[17];
  const float* Wih = (const float*)d_in[18];
  const float* Whh = (const float*)d_in[19];
  const float* bih = (const float*)d_in[20];
  const float* bhh = (const float*)d_in[21];
  const float* hW1 = (const float*)d_in[22];
  const float* hb1 = (const float*)d_in[23];
  const float* hW2 = (const float*)d_in[24];
  const float* hb2 = (const float*)d_in[25];

  char* ws = (char*)d_ws;
  f16* xh = (f16*)ws;      ws += (size_t)NB * NH * 2;
  f16* t0h = (f16*)ws;     ws += (size_t)NB * NH * 2;
  f16* endh = (f16*)ws;    ws += (size_t)NB * NH * 2;
  f16* tauh = (f16*)ws;    ws += (size_t)NB * NL * NH * 2;
  f16* nodeh = (f16*)ws;   ws += (size_t)NB * 2 * NL * NH * 2;
  f16* coordh = (f16*)ws;  ws += (size_t)NB * 2 * NL * NH * 2;
  f16* Wf = (f16*)ws;      ws += (size_t)NSF * 4096 * 2;
  f16* Wih16 = (f16*)ws;   ws += (size_t)7 * 512 * NH * 2;
  f16* Whh16 = (f16*)ws;   ws += (size_t)7 * 512 * NH * 2;
  float* bsum = (float*)ws;

  prep_kernel<<<1024, 256, 0, stream>>>(
      x, t0, tau, endi, coords, Wx1, Wx2, bx2, Wres, bres, Wnode, Wtau, btau,
      Wend1, Wend2, bend2, Wcoord, Wih, Whh, bih, bhh,
      xh, t0h, endh, tauh, coordh, Wf, Wih16, Whh16, bsum);
  node_gemm<<<256, 512, 0, stream>>>(node, Wf, nodeh);
  lstm_run<<<224, 512, 0, stream>>>(xh, t0h, endh, tauh, nodeh, coordh,
                                    Wih16, Whh16, bsum, hW1, hb1, hW2, hb2,
                                    (float*)d_out);
}

// Round 17
// 245.391 us; speedup vs baseline: 1.0554x; 1.0554x over previous
//
#include <hip/hip_runtime.h>
#include <hip/hip_fp16.h>

typedef _Float16 f16;
typedef _Float16 f16x8 __attribute__((ext_vector_type(8)));
typedef float f32x4 __attribute__((ext_vector_type(4)));

#define NB 512
#define NL 16
#define NK 10000
#define NH 128
#define NSF 320    // Wf 32-k sub-steps, zero-padded (80 tiles x 4)
#define NT 80      // 128-k tiles (tiles 78.5+ are zero-padded via Wf)

__device__ __forceinline__ float fast_exp2(float x) {
#if __has_builtin(__builtin_amdgcn_exp2f)
  return __builtin_amdgcn_exp2f(x);
#else
  return exp2f(x);
#endif
}
__device__ __forceinline__ float fast_rcp(float x) {
#if __has_builtin(__builtin_amdgcn_rcpf)
  return __builtin_amdgcn_rcpf(x);
#else
  return 1.f / x;
#endif
}
__device__ __forceinline__ float sigf(float x) {
  return fast_rcp(1.f + fast_exp2(-1.44269504f * x));
}
__device__ __forceinline__ float tanh_fast(float x) {
  return 2.f * fast_rcp(1.f + fast_exp2(-2.88539008f * x)) - 1.f;
}

// ---------------------------------------------------------------- prep ------
// Wf: B in MFMA-fragment order: [s][nt][lane][e] with lane=(kg*16+lr),
// value = Wnode[col=nt*16+lr][k=s*32+kg*8+e], zero-padded past K=10000.
__global__ void prep_kernel(
    const float* __restrict__ x, const float* __restrict__ t0,
    const float* __restrict__ tau, const float* __restrict__ endi,
    const float* __restrict__ coords,
    const float* __restrict__ Wx1, const float* __restrict__ Wx2,
    const float* __restrict__ bx2, const float* __restrict__ Wres,
    const float* __restrict__ bres, const float* __restrict__ Wnode,
    const float* __restrict__ Wtau, const float* __restrict__ btau,
    const float* __restrict__ Wend1, const float* __restrict__ Wend2,
    const float* __restrict__ bend2, const float* __restrict__ Wcoord,
    const float* __restrict__ Wih, const float* __restrict__ Whh,
    const float* __restrict__ bih, const float* __restrict__ bhh,
    f16* __restrict__ xh, f16* __restrict__ t0h, f16* __restrict__ endh,
    f16* __restrict__ tauh, f16* __restrict__ coordh, f16* __restrict__ Wf,
    f16* __restrict__ Wih16, f16* __restrict__ Whh16, float* __restrict__ bsum) {
  const int tid0 = blockIdx.x * blockDim.x + threadIdx.x;
  const int stride = gridDim.x * blockDim.x;

  const int nWf = NSF * 4096;       // 1,310,720 (incl. zero tail)
  const int nW = 7 * 512 * NH;      // 458,752
  const int nb = 7 * 512;
  const int nxh = NB * NH;          // 65,536
  const int ntau = NB * NL * NH;    // 1,048,576
  const int nco = NB * 2 * NL * NH; // 2,097,152

  for (int i = tid0; i < nWf; i += stride) {
    const int s = i >> 12, r = i & 4095;
    const int nt = r >> 9, l2 = r & 511;
    const int lane = l2 >> 3, e = l2 & 7;
    const int kg = lane >> 4, lr = lane & 15;
    const int col = nt * 16 + lr;
    const int k = s * 32 + kg * 8 + e;
    Wf[i] = (k < NK) ? (f16)Wnode[(size_t)col * NK + k] : (f16)0.f;
  }
  for (int i = tid0; i < nW; i += stride) {
    Wih16[i] = (f16)Wih[i];
    Whh16[i] = (f16)Whh[i];
  }
  for (int i = tid0; i < nb; i += stride) bsum[i] = bih[i] + bhh[i];
  for (int i = tid0; i < nxh; i += stride) {
    const int b = i >> 7, h = i & 127;
    const float s = x[2 * b] * Wx1[0] + x[2 * b + 1] * Wx1[1];
    xh[i] = (f16)tanhf(s * Wx2[h] + bx2[h]);
    t0h[i] = (f16)tanhf(t0[b] * Wres[h] + bres[h]);
    const float e = endi[2 * b] * Wend1[0] + endi[2 * b + 1] * Wend1[1];
    endh[i] = (f16)(e * Wend2[h] + bend2[h]);
  }
  for (int i = tid0; i < ntau; i += stride) {
    const int h = i & 127, bl = i >> 7;
    tauh[i] = (f16)tanhf(tau[bl] * Wtau[h] + btau[h]);
  }
  for (int i = tid0; i < nco; i += stride) {
    const int h = i & 127, br = i >> 7;
    coordh[i] = (f16)(coords[2 * br] * Wcoord[2 * h] +
                      coords[2 * br + 1] * Wcoord[2 * h + 1]);
  }
}

// ------------------------------------------------------------ node GEMM -----
// C(16384x128,f16) = A(16384x10000,f32) * W^T. Grid 256 wgs x 64 rows,
// full K (NT=80 tiles of 128 k, tail zero-padded via Wf). A: nontemporal
// dwordx4 -> VGPR -> swizzled ds_write (R15), issued in TILE PAIRS with
// per-row back-to-back chunks (R9 adjacency: each row gets 1 KB adjacent
// issues). Pair-granular schedule, ring-4 LDS (128 KB), ONE barrier per
// 2 tiles, audited counted vmcnt: every wait leaves 12 loads (a full
// A-pair + one B-set) in flight -- the HBM queue never empties.
// Wave = (kw: 64-k half, cp: 32 cols); B 1x redundancy; kw-combine epilogue.
__global__ __launch_bounds__(512, 2) void node_gemm(const float* __restrict__ A,
                                                    const f16* __restrict__ Wf,
                                                    f16* __restrict__ Cn) {
  __shared__ char lds[4][32768];
  const int tid = threadIdx.x;
  const int w = tid >> 6, l = tid & 63;
  const int lr = l & 15, kg = l >> 4;
  const int r0 = blockIdx.x * 64;
  char* lds0 = &lds[0][0];

  // ---- staging: slot i covers rows w*8+i*2+(l>>5); 32 lanes = 512 B/row ----
  const char* ap[4];
  int bnd[4], wdo[4];
#pragma unroll
  for (int i = 0; i < 4; i++) {
    const int row = w * 8 + i * 2 + (l >> 5);
    const int off = (l & 31) * 16;
    ap[i] = (const char*)A + (size_t)(r0 + row) * 40000 + off;
    bnd[i] = 39984 - off;  // clamp keeps 16B in-bounds; Wf zero-pad kills it
    wdo[i] = row * 512 + (off ^ ((row & 7) << 4));
  }

  // ---- compute: wave = (kw = w&1: 64-k half, cp = w>>1: 32 cols) ----
  const int kw = w & 1, cp = w >> 1;
  int rdoA[4][2][2];  // [row-group][k-slice][half]
#pragma unroll
  for (int rg = 0; rg < 4; rg++) {
    const int row = rg * 16 + lr;
    const int sw = (row & 7) << 4;
#pragma unroll
    for (int ks = 0; ks < 2; ks++)
#pragma unroll
      for (int h = 0; h < 2; h++)
        rdoA[rg][ks][h] =
            row * 512 + ((kw * 256 + ks * 128 + kg * 32 + h * 16) ^ sw);
  }

  f32x4 acc[4][2];
#pragma unroll
  for (int rg = 0; rg < 4; rg++)
#pragma unroll
    for (int j = 0; j < 2; j++) {
      f32x4 z = {0.f, 0.f, 0.f, 0.f};
      acc[rg][j] = z;
    }

  // load A tiles t and t+1 with per-row ADJACENT issues (R9): slot i's two
  // chunks (tile t, tile t+1) are back-to-back -> 1 KB adjacent per row.
  auto burstA = [&](int t, f32x4 (&ra)[4], f32x4 (&rb)[4]) {
    const int tb0 = t * 512, tb1 = tb0 + 512;
#pragma unroll
    for (int i = 0; i < 4; i++) {
      ra[i] = __builtin_nontemporal_load(
          (const f32x4*)(ap[i] + (tb0 < bnd[i] ? tb0 : bnd[i])));
      rb[i] = __builtin_nontemporal_load(
          (const f32x4*)(ap[i] + (tb1 < bnd[i] ? tb1 : bnd[i])));
    }
  };

  auto dswrite = [&](int t, const f32x4 (&r)[4]) {
    char* db = lds0 + (t & 3) * 32768;
#pragma unroll
    for (int i = 0; i < 4; i++) *(f32x4*)(db + wdo[i]) = r[i];
  };

  // this wave's unique B share for 128-k tile t: 2 cols x 2 k-slices
  auto loadB = [&](int t, f16x8 (&B)[2][2]) {
    const f16* bp = Wf + (size_t)(4 * t + 2 * kw) * 4096 + cp * 1024 + l * 8;
#pragma unroll
    for (int j = 0; j < 2; j++)
#pragma unroll
      for (int ks = 0; ks < 2; ks++)
        B[j][ks] = *(const f16x8*)(bp + (size_t)ks * 4096 + j * 512);
  };

  auto compute = [&](int t, const f16x8 (&B)[2][2]) {
    const char* cb = lds0 + (t & 3) * 32768;
#pragma unroll
    for (int ks = 0; ks < 2; ks++)
#pragma unroll
      for (int rg = 0; rg < 4; rg++) {
        const f32x4 a0 = *(const f32x4*)(cb + rdoA[rg][ks][0]);
        const f32x4 a1 = *(const f32x4*)(cb + rdoA[rg][ks][1]);
        f16x8 af;
        af[0] = (f16)a0[0]; af[1] = (f16)a0[1];
        af[2] = (f16)a0[2]; af[3] = (f16)a0[3];
        af[4] = (f16)a1[0]; af[5] = (f16)a1[1];
        af[6] = (f16)a1[2]; af[7] = (f16)a1[3];
#pragma unroll
        for (int j = 0; j < 2; j++)
          acc[rg][j] = __builtin_amdgcn_mfma_f32_16x16x32_f16(
              af, B[j][ks], acc[rg][j], 0, 0, 0);
      }
  };

  f32x4 RA0[4], RA1[4], RB0[4], RB1[4];
  f16x8 B0[2][2], B1[2][2];

// pair body: tiles (E, E+1); CUR regs hold their A (validated); bursts the
// pair E+4 into the same reg set (read 2 pairs later). VM1S retires
// {A(E+2..3), B(E)}; VM2S retires {B(E+1)}; 12 loads stay in flight.
#define PBODY(E, C0, C1, VM1S, VM2S, DOB, DOL)                        \
  do {                                                                \
    dswrite((E), C0);                                                 \
    dswrite((E) + 1, C1);                                             \
    loadB((E) + 1, B1);                                               \
    if (DOB) burstA((E) + 4, C0, C1);                                 \
    asm volatile("s_waitcnt lgkmcnt(0)" ::: "memory");                \
    __builtin_amdgcn_s_barrier();                                     \
    asm volatile("s_waitcnt vmcnt(" VM1S ")" ::: "memory");           \
    compute((E), B0);                                                 \
    if (DOL) loadB((E) + 2, B0);                                      \
    asm volatile("s_waitcnt vmcnt(" VM2S ")" ::: "memory");           \
    compute((E) + 1, B1);                                             \
  } while (0)

  // prologue (FIFO: b01[8], B0[4], b23[8]); vmcnt(12) validates RA.
  burstA(0, RA0, RA1);
  loadB(0, B0);
  burstA(2, RB0, RB1);
  asm volatile("s_waitcnt vmcnt(12)" ::: "memory");

  PBODY(0, RA0, RA1, "20", "12", true, true);
  PBODY(2, RB0, RB1, "12", "12", true, true);
  for (int e = 4; e <= 72; e += 4) {
    PBODY(e, RA0, RA1, "12", "12", true, true);
    PBODY(e + 2, RB0, RB1, "12", "12", true, true);
  }
  PBODY(76, RA0, RA1, "4", "4", false, true);
  PBODY(78, RB0, RB1, "4", "0", false, false);
#undef PBODY

  // ---- combine kw halves via LDS bounce, then write C f16 ----
  __syncthreads();  // all computes done
  if (kw == 1) {
#pragma unroll
    for (int rg = 0; rg < 4; rg++)
#pragma unroll
      for (int j = 0; j < 2; j++) {
        const int tl = cp * 8 + rg * 2 + j;
        *(f32x4*)(lds0 + tl * 1024 + l * 16) = acc[rg][j];
      }
  }
  __syncthreads();
  if (kw == 0) {
#pragma unroll
    for (int rg = 0; rg < 4; rg++)
#pragma unroll
      for (int j = 0; j < 2; j++) {
        const int tl = cp * 8 + rg * 2 + j;
        const f32x4 p = *(const f32x4*)(lds0 + tl * 1024 + l * 16);
        const f32x4 s = acc[rg][j] + p;
        f16* crow =
            Cn + (size_t)(r0 + rg * 16 + kg * 4) * NH + cp * 32 + j * 16 + lr;
#pragma unroll
        for (int jr = 0; jr < 4; jr++) crow[(size_t)jr * NH] = (f16)s[jr];
      }
  }
}

// --------------------------------------------------------------- LSTM -------
// grid: 7 k's x 32 batch-chunks of 16. One wg = 8 waves (512 thr); wave w
// owns hidden units [w*16, w*16+16) across all four gates (4 gate-tiles).
// Wih/Whh fragments in VGPRs (~128), x prefetched 1 step ahead. x-MFMAs run
// before h-MFMAs so the ds_read(h) latency hides under them.
__global__ __launch_bounds__(512, 2) void lstm_run(
    const f16* __restrict__ xh, const f16* __restrict__ t0h,
    const f16* __restrict__ endh, const f16* __restrict__ tauh,
    const f16* __restrict__ nodeh, const f16* __restrict__ coordh,
    const f16* __restrict__ Wih16, const f16* __restrict__ Whh16,
    const float* __restrict__ bsum, const float* __restrict__ hW1,
    const float* __restrict__ hb1, const float* __restrict__ hW2,
    const float* __restrict__ hb2, float* __restrict__ out) {
  __shared__ f16 hbuf[2][16 * NH];  // double-buffered h, XOR-swizzled bytes
  __shared__ float hu[16 * NH];

  const int k = blockIdx.x >> 5;
  const int b0 = (blockIdx.x & 31) << 4;
  const int w = threadIdx.x >> 6;
  const int l = threadIdx.x & 63;
  const int lr = l & 15, kg = l >> 4;

  int len;
  switch (k) {
    case 0: len = 83; break;
    case 1: len = 19; break;
    case 2: len = 32; break;
    case 3: len = 32; break;
    case 4: len = 51; break;
    case 5: len = 64; break;
    default: len = 51; break;
  }

  // per-step input fragment pointer (wave-uniform select logic)
  auto xptr = [&](int t) -> const f16* {
    const f16* cb; int bstr, idx;
    if (k == 2) { cb = nodeh; bstr = 32 * NH; idx = t; }
    else if (k == 3) { cb = coordh; bstr = 32 * NH; idx = t; }
    else if (k == 5) {
      const int q = t >> 2, r = t & 3;
      cb = (r == 0 || r == 2) ? nodeh : coordh;
      bstr = 32 * NH;
      idx = 2 * q + ((r >= 2) ? 1 : 0);
    } else {
      if (t == 0) { cb = xh; bstr = NH; idx = 0; }
      else if (t == 1) { cb = t0h; bstr = NH; idx = 0; }
      else if (t == len - 1) { cb = endh; bstr = NH; idx = 0; }
      else {
        const int u = t - 2;
        if (k == 0) {
          const int q = u / 5, r = u - 5 * q;
          if (r == 0) { cb = tauh; bstr = 16 * NH; idx = q; }
          else if (r == 1) { cb = nodeh; bstr = 32 * NH; idx = 2 * q; }
          else if (r == 2) { cb = coordh; bstr = 32 * NH; idx = 2 * q; }
          else if (r == 3) { cb = nodeh; bstr = 32 * NH; idx = 2 * q + 1; }
          else { cb = coordh; bstr = 32 * NH; idx = 2 * q + 1; }
        } else if (k == 1) { cb = tauh; bstr = 16 * NH; idx = u; }
        else if (k == 4) {
          const int q = u / 3, r = u - 3 * q;
          if (r == 0) { cb = tauh; bstr = 16 * NH; idx = q; }
          else { cb = nodeh; bstr = 32 * NH; idx = 2 * q + (r - 1); }
        } else {  // k == 6
          const int q = u / 3, r = u - 3 * q;
          if (r == 0) { cb = tauh; bstr = 16 * NH; idx = q; }
          else { cb = coordh; bstr = 32 * NH; idx = 2 * q + (r - 1); }
        }
      }
    }
    return cb + (size_t)(b0 + lr) * bstr + idx * NH + kg * 8;
  };

  // ---- load weight fragments into registers ----
  // wave w owns hidden cols [w*16, w*16+16); gate g's row block = g*128.
  f16x8 Wh[4][4], Wi[4][4];
  float bias[4];
  {
    const f16* whb = Whh16 + (size_t)k * 512 * NH;
    const f16* wib = Wih16 + (size_t)k * 512 * NH;
#pragma unroll
    for (int g = 0; g < 4; g++) {
      const int col = g * 128 + w * 16 + lr;
      bias[g] = bsum[k * 512 + col];
#pragma unroll
      for (int kc = 0; kc < 4; kc++) {
        Wh[kc][g] = *(const f16x8*)(whb + (size_t)col * NH + kc * 32 + kg * 8);
        Wi[kc][g] = *(const f16x8*)(wib + (size_t)col * NH + kc * 32 + kg * 8);
      }
    }
  }

  char* lds0 = (char*)&hbuf[0][0];
  // zero h buffer 0 (h0 = 0): 512 threads x 8 B = 4096 B
  *(unsigned long long*)(lds0 + threadIdx.x * 8) = 0ull;
  __syncthreads();

  float c[4] = {0, 0, 0, 0};

  // precomputed swizzled LDS byte offsets (constant across t)
  int rdo[4];
#pragma unroll
  for (int kc = 0; kc < 4; kc++) {
    const int colb = (kc * 32 + kg * 8) * 2;
    rdo[kc] = lr * 256 + (colb ^ ((lr & 7) << 4));
  }
  int wro[4];
#pragma unroll
  for (int jr = 0; jr < 4; jr++) {
    const int hrow = kg * 4 + jr;
    const int hcol = w * 16 + lr;
    wro[jr] = hrow * 256 + ((hcol * 2) ^ ((hrow & 7) << 4));
  }

  // prime x for t=0
  f16x8 axc[4];
  {
    const f16* xp = xptr(0);
#pragma unroll
    for (int kc = 0; kc < 4; kc++) axc[kc] = *(const f16x8*)(xp + kc * 32);
  }

  int cur = 0;
  for (int t = 0; t < len; t++) {
    char* rb = lds0 + cur * 4096;
    f16x8 ah[4];
#pragma unroll
    for (int kc = 0; kc < 4; kc++) ah[kc] = *(const f16x8*)(rb + rdo[kc]);

    // prefetch next-step x into registers (hidden under MFMA+gates+barrier)
    f16x8 axn[4];
    if (t + 1 < len) {
      const f16* xp = xptr(t + 1);
#pragma unroll
      for (int kc = 0; kc < 4; kc++) axn[kc] = *(const f16x8*)(xp + kc * 32);
    }

    f32x4 acc[4];
#pragma unroll
    for (int g = 0; g < 4; g++) {
      f32x4 binit = {bias[g], bias[g], bias[g], bias[g]};
      acc[g] = binit;
    }
    // x-part first (register operands ready) -> hides ds_read(h) latency
#pragma unroll
    for (int kc = 0; kc < 4; kc++)
#pragma unroll
      for (int g = 0; g < 4; g++)
        acc[g] = __builtin_amdgcn_mfma_f32_16x16x32_f16(axc[kc], Wi[kc][g], acc[g], 0, 0, 0);
#pragma unroll
    for (int kc = 0; kc < 4; kc++)
#pragma unroll
      for (int g = 0; g < 4; g++)
        acc[g] = __builtin_amdgcn_mfma_f32_16x16x32_f16(ah[kc], Wh[kc][g], acc[g], 0, 0, 0);

    // gates: acc[0]=i acc[1]=f acc[2]=g acc[3]=o
    char* wb = lds0 + (cur ^ 1) * 4096;
#pragma unroll
    for (int jr = 0; jr < 4; jr++) {
      const float iv = acc[0][jr];
      const float fv = acc[1][jr];
      const float gv = acc[2][jr];
      const float ov = acc[3][jr];
      const float cn = sigf(fv) * c[jr] + sigf(iv) * tanh_fast(gv);
      c[jr] = cn;
      const float hn = sigf(ov) * tanh_fast(cn);
      *(f16*)(wb + wro[jr]) = (f16)hn;
    }
    __syncthreads();
#pragma unroll
    for (int kc = 0; kc < 4; kc++) axc[kc] = axn[kc];
    cur ^= 1;
  }

  // ---- head: out = tanh(h @ W1^T + b1) @ W2^T + b2 ----
  {
    char* rb = lds0 + cur * 4096;
    f16x8 ah[4];
#pragma unroll
    for (int kc = 0; kc < 4; kc++) ah[kc] = *(const f16x8*)(rb + rdo[kc]);
    const float* W1 = hW1 + (size_t)k * NH * NH;
    const int col = w * 16 + lr;
    f32x4 hacc;
    {
      const float b1 = hb1[k * NH + col];
      f32x4 binit = {b1, b1, b1, b1};
      hacc = binit;
    }
#pragma unroll
    for (int kc = 0; kc < 4; kc++) {
      const float* wrow = W1 + (size_t)col * NH + kc * 32 + kg * 8;
      const f32x4 w0 = *(const f32x4*)(wrow);
      const f32x4 w1 = *(const f32x4*)(wrow + 4);
      f16x8 wv;
      wv[0] = (f16)w0[0]; wv[1] = (f16)w0[1]; wv[2] = (f16)w0[2]; wv[3] = (f16)w0[3];
      wv[4] = (f16)w1[0]; wv[5] = (f16)w1[1]; wv[6] = (f16)w1[2]; wv[7] = (f16)w1[3];
      hacc = __builtin_amdgcn_mfma_f32_16x16x32_f16(ah[kc], wv, hacc, 0, 0, 0);
    }
#pragma unroll
    for (int jr = 0; jr < 4; jr++)
      hu[(kg * 4 + jr) * NH + col] = tanh_fast(hacc[jr]);
  }
  __syncthreads();
  if (w == 0) {
    const int b = l >> 2, part = l & 3;
    const float* W2 = hW2 + (size_t)k * NH;
    float s = 0.f;
#pragma unroll
    for (int j = 0; j < 32; j++)
      s += hu[b * NH + part * 32 + j] * W2[part * 32 + j];
    s += __shfl_xor(s, 1);
    s += __shfl_xor(s, 2);
    if (part == 0) out[k * NB + b0 + b] = s + hb2[k];
  }
}

// ------------------------------------------------------------- launch -------
extern "C" void kernel_launch(void* const* d_in, const int* in_sizes, int n_in,
                              void* d_out, int out_size, void* d_ws, size_t ws_size,
                              hipStream_t stream) {
  (void)in_sizes; (void)n_in; (void)out_size; (void)ws_size;
  const float* x = (const float*)d_in[0];
  const float* t0 = (const float*)d_in[1];
  const float* node = (const float*)d_in[2];
  const float* tau = (const float*)d_in[3];
  const float* endi = (const float*)d_in[4];
  const float* coords = (const float*)d_in[5];
  const float* Wx1 = (const float*)d_in[6];
  const float* Wx2 = (const float*)d_in[7];
  const float* bx2 = (const float*)d_in[8];
  const float* Wres = (const float*)d_in[9];
  const float* bres = (const float*)d_in[10];
  const float* Wnode = (const float*)d_in[11];
  const float* Wtau = (const float*)d_in[12];
  const float* btau = (const float*)d_in[13];
  const float* Wend1 = (const float*)d_in[14];
  const float* Wend2 = (const float*)d_in[15];
  const float* bend2 = (const float*)d_in[16];
  const float* Wcoord = (const float*)d_in[17];
  const float* Wih = (const float*)d_in[18];
  const float* Whh = (const float*)d_in[19];
  const float* bih = (const float*)d_in[20];
  const float* bhh = (const float*)d_in[21];
  const float* hW1 = (const float*)d_in[22];
  const float* hb1 = (const float*)d_in[23];
  const float* hW2 = (const float*)d_in[24];
  const float* hb2 = (const float*)d_in[25];

  char* ws = (char*)d_ws;
  f16* xh = (f16*)ws;      ws += (size_t)NB * NH * 2;
  f16* t0h = (f16*)ws;     ws += (size_t)NB * NH * 2;
  f16* endh = (f16*)ws;    ws += (size_t)NB * NH * 2;
  f16* tauh = (f16*)ws;    ws += (size_t)NB * NL * NH * 2;
  f16* nodeh = (f16*)ws;   ws += (size_t)NB * 2 * NL * NH * 2;
  f16* coordh = (f16*)ws;  ws += (size_t)NB * 2 * NL * NH * 2;
  f16* Wf = (f16*)ws;      ws += (size_t)NSF * 4096 * 2;
  f16* Wih16 = (f16*)ws;   ws += (size_t)7 * 512 * NH * 2;
  f16* Whh16 = (f16*)ws;   ws += (size_t)7 * 512 * NH * 2;
  float* bsum = (float*)ws;

  prep_kernel<<<1024, 256, 0, stream>>>(
      x, t0, tau, endi, coords, Wx1, Wx2, bx2, Wres, bres, Wnode, Wtau, btau,
      Wend1, Wend2, bend2, Wcoord, Wih, Whh, bih, bhh,
      xh, t0h, endh, tauh, coordh, Wf, Wih16, Whh16, bsum);
  node_gemm<<<256, 512, 0, stream>>>(node, Wf, nodeh);
  lstm_run<<<224, 512, 0, stream>>>(xh, t0h, endh, tauh, nodeh, coordh,
                                    Wih16, Whh16, bsum, hW1, hb1, hW2, hb2,
                                    (float*)d_out);
}